// Round 19
// baseline (1909.892 us; speedup 1.0000x reference)
//
#include <hip/hip_runtime.h>
#include <stdint.h>

// ---------------------------------------------------------------------------
// AdaptiveDiffAttention on MI355X (gfx950)
// Round 19: r17 tile geometry (256x256, BK=128, traffic-optimal) + single
// 64KB LDS buffer -> 2 blocks/CU (launch_bounds(512,4), VGPR<=128).
// Per tile: {vmcnt(0); barrier; 24 ds_read + 32 MFMA; barrier; stage t+1}.
// Cross-block overlap (proven r18) hides the stage drain. Numerics = r17.
// ---------------------------------------------------------------------------

#define ATT_SCALE 0.0625f // 256^-0.5

typedef __attribute__((ext_vector_type(8)))  short   s16x8;
typedef __attribute__((ext_vector_type(4)))  float   f32x4;
typedef __attribute__((ext_vector_type(2)))  float   f32x2;
typedef __attribute__((ext_vector_type(8)))  int     i32x8;
typedef __attribute__((ext_vector_type(8)))  unsigned short u16x8;
typedef __attribute__((ext_vector_type(4)))  unsigned short u16x4;

__device__ __forceinline__ unsigned short f2bf(float f) {
  unsigned u = __float_as_uint(f);
  u += 0x7FFFu + ((u >> 16) & 1u);   // RNE
  return (unsigned short)(u >> 16);
}
__device__ __forceinline__ float bf2f(unsigned short s) {
  return __uint_as_float((unsigned)s << 16);
}

__device__ __forceinline__ unsigned char f2e4m3(float f) {
  unsigned u = __float_as_uint(f);
  unsigned s = (u >> 24) & 0x80u;
  float a = fabsf(f);
  if (a >= 448.f) return (unsigned char)(s | 0x7E);
  if (a < 0.0009765625f) return (unsigned char)s;
  int e = (int)((u >> 23) & 0xFF) - 127;
  if (e < -6) {
    int q = (int)rintf(a * 512.f);
    if (q >= 8) return (unsigned char)(s | 0x08);
    return (unsigned char)(s | q);
  }
  unsigned mant = u & 0x7FFFFFu;
  unsigned mr = mant + 0x7FFFFu + ((mant >> 20) & 1u);
  e += (int)(mr >> 23);
  mant = (mr >> 20) & 7u;
  if (e > 8) return (unsigned char)(s | 0x7E);
  return (unsigned char)(s | ((e + 7) << 3) | mant);
}
__device__ __forceinline__ float e4m3f(unsigned v) {
  unsigned e = (v >> 3) & 15u, m = v & 7u;
  float mag = (e == 0) ? (float)m * 0.001953125f
                       : __uint_as_float(((e + 120u) << 23) | (m << 20));
  return (v & 0x80u) ? -mag : mag;
}

__device__ __forceinline__ unsigned char cvt1_fp8(float v) {
#if __has_builtin(__builtin_amdgcn_cvt_pk_fp8_f32)
  return (unsigned char)(__builtin_amdgcn_cvt_pk_fp8_f32(v, v, 0, false) & 0xff);
#else
  return f2e4m3(v);
#endif
}

__device__ __forceinline__ void dec8(uint2 p, float* o) {
#if __has_builtin(__builtin_amdgcn_cvt_pk_f32_fp8)
  f32x2 a = __builtin_amdgcn_cvt_pk_f32_fp8((int)p.x, false);
  f32x2 b = __builtin_amdgcn_cvt_pk_f32_fp8((int)p.x, true);
  f32x2 c = __builtin_amdgcn_cvt_pk_f32_fp8((int)p.y, false);
  f32x2 d = __builtin_amdgcn_cvt_pk_f32_fp8((int)p.y, true);
  o[0] = a[0]; o[1] = a[1]; o[2] = b[0]; o[3] = b[1];
  o[4] = c[0]; o[5] = c[1]; o[6] = d[0]; o[7] = d[1];
#else
#pragma unroll
  for (int j = 0; j < 4; ++j) o[j]     = e4m3f((p.x >> (8 * j)) & 255u);
#pragma unroll
  for (int j = 0; j < 4; ++j) o[4 + j] = e4m3f((p.y >> (8 * j)) & 255u);
#endif
}

__device__ __forceinline__ void async16(const void* g, void* l) {
  __builtin_amdgcn_global_load_lds((__attribute__((address_space(1))) void*)g,
                                   (__attribute__((address_space(3))) void*)l,
                                   16, 0, 0);
}

// ---------------------------------------------------------------------------
// MX-fp8 proj GEMM + fused lambda. 512 threads, 64KB LDS (2 blocks/CU).
// Blocks 0..127: lambda. Blocks 128+: [32768,1024]fp8 @ [5120,1024]^T fp8,
// 256x256 tile, BK=128, single buffer.
//   bn<4096 -> fp8 chunk-blocked qk8 (in-chunk col perm, dot-invariant);
//   bn>=4096 -> fp8 row-major vbuf8.
// ---------------------------------------------------------------------------
__global__ __launch_bounds__(512, 4)
void gemm_mx(const unsigned char* __restrict__ A,
             const unsigned char* __restrict__ Bt,
             const float* __restrict__ bias,
             unsigned char* __restrict__ Cout,
             unsigned char* __restrict__ Vout,
             int NN,
             const unsigned short* __restrict__ xbf,
             const unsigned short* __restrict__ lamBt,
             const float* __restrict__ lamL1b,
             const float* __restrict__ lamL2w,
             float* __restrict__ lamp)
{
  __shared__ __align__(16) char lds[65536];
  const int tid  = threadIdx.x;
  const int lane = tid & 63, w = tid >> 6;
  const int wm = w >> 2, wn = w & 3;
  const int li = lane & 15, lc = lane >> 4;

  if (blockIdx.x < 128) {
    // ---- fused lambda block (r12-proven) ----
    const int bm_l = blockIdx.x * 128;
    const int t = tid;
    const size_t aSrc  = (size_t)(bm_l + (t >> 2)) * 2048 + (t & 3) * 8;
    const size_t b0Src = (size_t)(t >> 2) * 2048 + (t & 3) * 8;
    const size_t b1Src = (size_t)(128 + (t >> 2)) * 2048 + (t & 3) * 8;

    f32x4 acc[4][4];
#pragma unroll
    for (int i = 0; i < 4; ++i)
#pragma unroll
      for (int j = 0; j < 4; ++j) acc[i][j] = (f32x4)0.f;

    for (int k0 = 0; k0 < 2048; k0 += 32) {
      async16(xbf   + aSrc  + k0, lds + w * 1024);
      async16(lamBt + b0Src + k0, lds + 8192 + w * 1024);
      async16(lamBt + b1Src + k0, lds + 16384 + w * 1024);
      __syncthreads();
      s16x8 aR[4], bR[4];
#pragma unroll
      for (int m = 0; m < 4; ++m)
        aR[m] = *(const s16x8*)(lds + ((w >> 2) * 64 + m * 16 + li) * 64 + lc * 16);
#pragma unroll
      for (int n = 0; n < 4; ++n)
        bR[n] = *(const s16x8*)(lds + 8192 + ((w & 3) * 64 + n * 16 + li) * 64 + lc * 16);
#pragma unroll
      for (int m = 0; m < 4; ++m)
#pragma unroll
        for (int n = 0; n < 4; ++n)
          acc[m][n] = __builtin_amdgcn_mfma_f32_16x16x32_bf16(aR[m], bR[n], acc[m][n], 0, 0, 0);
      __syncthreads();
    }

    float l2v[4], bvv[4];
#pragma unroll
    for (int n = 0; n < 4; ++n) {
      const int col = (w & 3) * 64 + n * 16 + li;
      l2v[n] = lamL2w[col];
      bvv[n] = lamL1b[col];
    }
#pragma unroll
    for (int m = 0; m < 4; ++m)
#pragma unroll
      for (int j = 0; j < 4; ++j) {
        float part = 0.f;
#pragma unroll
        for (int n = 0; n < 4; ++n)
          part += fmaxf(acc[m][n][j] + bvv[n], 0.f) * l2v[n];
        part += __shfl_xor(part, 1, 64);
        part += __shfl_xor(part, 2, 64);
        part += __shfl_xor(part, 4, 64);
        part += __shfl_xor(part, 8, 64);
        if ((lane & 15) == 0)
          atomicAdd(lamp + bm_l + (w >> 2) * 64 + m * 16 + lc * 4 + j, part);
      }
    return;
  }

  // ---- MX proj path: 256x256 tile, single 64KB buffer ----
  const int bid = blockIdx.x - 128;
  const int nwg = 2560;
  const int swz = (bid & 7) * (nwg >> 3) + (bid >> 3);
  const int bm = (swz / NN) * 256;
  const int bn = (swz % NN) * 256;

  const int grow   = lane >> 3;
  const int gchunk = ((lane & 7) ^ grow) * 16;
  size_t aSrc[4], bSrc[4];
  int dstKB[4];
#pragma unroll
  for (int i = 0; i < 4; ++i) {
    const int rr = (i * 8 + w) * 8 + grow;
    aSrc[i] = (size_t)(bm + rr) * 1024 + gchunk;
    bSrc[i] = (size_t)(bn + rr) * 1024 + gchunk;
    dstKB[i] = (i * 8 + w) * 1024;
  }

  const int x7   = li & 7;
  const int off0 = ((2 * lc)     ^ x7) * 16;
  const int off1 = ((2 * lc + 1) ^ x7) * 16;
  const int aRow = (wm * 128 + li) * 128;
  const int bRow = 32768 + (wn * 64 + li) * 128;

  f32x4 acc[8][4];
#pragma unroll
  for (int m = 0; m < 8; ++m)
#pragma unroll
    for (int n = 0; n < 4; ++n) acc[m][n] = (f32x4)0.f;

  // stage tile 0
#pragma unroll
  for (int i = 0; i < 4; ++i) {
    async16(A  + aSrc[i], lds + dstKB[i]);
    async16(Bt + bSrc[i], lds + 32768 + dstKB[i]);
  }

  for (int t = 0; t < 8; ++t) {
    asm volatile("s_waitcnt vmcnt(0)" ::: "memory");
    __builtin_amdgcn_s_barrier();

    i32x8 bF[4];
#pragma unroll
    for (int nf = 0; nf < 4; ++nf) {
      const char* p = lds + bRow + nf * 2048;
      uint4* bp = (uint4*)&bF[nf];
      bp[0] = *(const uint4*)(p + off0);
      bp[1] = *(const uint4*)(p + off1);
    }
#pragma unroll
    for (int mh = 0; mh < 2; ++mh) {
      i32x8 aF[4];
#pragma unroll
      for (int mf = 0; mf < 4; ++mf) {
        const char* p = lds + aRow + (mh * 4 + mf) * 2048;
        uint4* ap = (uint4*)&aF[mf];
        ap[0] = *(const uint4*)(p + off0);
        ap[1] = *(const uint4*)(p + off1);
      }
      __builtin_amdgcn_s_setprio(1);
#pragma unroll
      for (int mf = 0; mf < 4; ++mf)
#pragma unroll
        for (int nf = 0; nf < 4; ++nf)
          acc[mh * 4 + mf][nf] = __builtin_amdgcn_mfma_scale_f32_16x16x128_f8f6f4(
              aF[mf], bF[nf], acc[mh * 4 + mf][nf],
              0, 0, 0, 0x7F7F7F7F, 0, 0x7F7F7F7F);
      __builtin_amdgcn_s_setprio(0);
    }
    __builtin_amdgcn_s_barrier();
    if (t < 7) {
      const size_t kt = (size_t)(t + 1) * 128;
#pragma unroll
      for (int i = 0; i < 4; ++i) {
        async16(A  + aSrc[i] + kt, lds + dstKB[i]);
        async16(Bt + bSrc[i] + kt, lds + 32768 + dstKB[i]);
      }
    }
  }

  float bv[4];
#pragma unroll
  for (int n = 0; n < 4; ++n) bv[n] = bias[bn + wn * 64 + n * 16 + li];

  if (bn < 4096) {
    // fp8 chunk-blocked epilogue -> qk8, packed dword LDS writes.
    unsigned char* wl0 = (unsigned char*)(lds + w * 8192);
#pragma unroll
    for (int mp = 0; mp < 4; ++mp) {
      unsigned char* wl = wl0 + (mp & 1) * 2560;
#pragma unroll
      for (int mi = 0; mi < 2; ++mi)
#pragma unroll
        for (int jj = 0; jj < 4; ++jj) {
          unsigned d = 0;
#pragma unroll
          for (int n = 0; n < 4; ++n) {
            float v = acc[mp * 2 + mi][n][jj] + bv[n];
            d |= (unsigned)cvt1_fp8(v) << (8 * n);
          }
          *(unsigned*)(wl + (mi * 16 + lc * 4 + jj) * 80 + li * 4) = d;
        }
      const size_t base = (size_t)((bm + wm * 128 + mp * 32) >> 5) * 131072
                        + (size_t)((bn >> 6) + wn) * 2048;
      uint4 v0 = *(const uint4*)(wl + (lane >> 2) * 80 + (lane & 3) * 16);
      *(uint4*)(Cout + base + lane * 16) = v0;
      uint4 v1 = *(const uint4*)(wl + (16 + (lane >> 2)) * 80 + (lane & 3) * 16);
      *(uint4*)(Cout + base + 1024 + lane * 16) = v1;
    }
  } else {
    // fp8 epilogue -> vbuf8 [.,1024] row-major
    unsigned char* wl0 = (unsigned char*)(lds + w * 8192);
    const int cb = bn - 4096;
#pragma unroll
    for (int mp = 0; mp < 4; ++mp) {
      unsigned char* wl = wl0 + (mp & 1) * 2560;
#pragma unroll
      for (int mi = 0; mi < 2; ++mi)
#pragma unroll
        for (int n = 0; n < 4; ++n)
#pragma unroll
          for (int jj = 0; jj < 4; ++jj) {
            float v = acc[mp * 2 + mi][n][jj] + bv[n];
            wl[(mi * 16 + lc * 4 + jj) * 72 + n * 16 + li] = cvt1_fp8(v);
          }
#pragma unroll
      for (int i = 0; i < 4; ++i) {
        const int rr = i * 8 + (lane >> 3);
        uint2 vv = *(const uint2*)(wl + rr * 72 + (lane & 7) * 8);
        const size_t gi = (size_t)(bm + wm * 128 + mp * 32 + rr) * 1024
                        + cb + wn * 64 + (lane & 7) * 8;
        *(uint2*)(Vout + gi) = vv;
      }
    }
  }
}

// ---------------------------------------------------------------------------
// MX-fp8 WO GEMM: out[32768,1024](f32) = abuf8 @ wot8^T + WOb + res(bf16).
// 256x256 tile, single 64KB buffer, 2 blocks/CU.
// ---------------------------------------------------------------------------
__global__ __launch_bounds__(512, 4)
void gemm_womx(const unsigned char* __restrict__ A,
               const unsigned char* __restrict__ Bt,
               const float* __restrict__ bias,
               float* __restrict__ Cout,
               const unsigned short* __restrict__ res)
{
  __shared__ __align__(16) char lds[65536];
  const int tid  = threadIdx.x;
  const int lane = tid & 63, w = tid >> 6;
  const int wm = w >> 2, wn = w & 3;
  const int li = lane & 15, lc = lane >> 4;

  const int swz = (blockIdx.x & 7) * 64 + (blockIdx.x >> 3);
  const int bm = (swz >> 2) * 256;
  const int bn = (swz & 3) * 256;

  const int grow   = lane >> 3;
  const int gchunk = ((lane & 7) ^ grow) * 16;
  size_t aSrc[4], bSrc[4];
  int dstKB[4];
#pragma unroll
  for (int i = 0; i < 4; ++i) {
    const int rr = (i * 8 + w) * 8 + grow;
    aSrc[i] = (size_t)(bm + rr) * 1024 + gchunk;
    bSrc[i] = (size_t)(bn + rr) * 1024 + gchunk;
    dstKB[i] = (i * 8 + w) * 1024;
  }

  const int x7   = li & 7;
  const int off0 = ((2 * lc)     ^ x7) * 16;
  const int off1 = ((2 * lc + 1) ^ x7) * 16;
  const int aRow = (wm * 128 + li) * 128;
  const int bRow = 32768 + (wn * 64 + li) * 128;

  f32x4 acc[8][4];
#pragma unroll
  for (int m = 0; m < 8; ++m)
#pragma unroll
    for (int n = 0; n < 4; ++n) acc[m][n] = (f32x4)0.f;

#pragma unroll
  for (int i = 0; i < 4; ++i) {
    async16(A  + aSrc[i], lds + dstKB[i]);
    async16(Bt + bSrc[i], lds + 32768 + dstKB[i]);
  }

  for (int t = 0; t < 8; ++t) {
    asm volatile("s_waitcnt vmcnt(0)" ::: "memory");
    __builtin_amdgcn_s_barrier();

    i32x8 bF[4];
#pragma unroll
    for (int nf = 0; nf < 4; ++nf) {
      const char* p = lds + bRow + nf * 2048;
      uint4* bp = (uint4*)&bF[nf];
      bp[0] = *(const uint4*)(p + off0);
      bp[1] = *(const uint4*)(p + off1);
    }
#pragma unroll
    for (int mh = 0; mh < 2; ++mh) {
      i32x8 aF[4];
#pragma unroll
      for (int mf = 0; mf < 4; ++mf) {
        const char* p = lds + aRow + (mh * 4 + mf) * 2048;
        uint4* ap = (uint4*)&aF[mf];
        ap[0] = *(const uint4*)(p + off0);
        ap[1] = *(const uint4*)(p + off1);
      }
      __builtin_amdgcn_s_setprio(1);
#pragma unroll
      for (int mf = 0; mf < 4; ++mf)
#pragma unroll
        for (int nf = 0; nf < 4; ++nf)
          acc[mh * 4 + mf][nf] = __builtin_amdgcn_mfma_scale_f32_16x16x128_f8f6f4(
              aF[mf], bF[nf], acc[mh * 4 + mf][nf],
              0, 0, 0, 0x7F7F7F7F, 0, 0x7F7F7F7F);
      __builtin_amdgcn_s_setprio(0);
    }
    __builtin_amdgcn_s_barrier();
    if (t < 7) {
      const size_t kt = (size_t)(t + 1) * 128;
#pragma unroll
      for (int i = 0; i < 4; ++i) {
        async16(A  + aSrc[i] + kt, lds + dstKB[i]);
        async16(Bt + bSrc[i] + kt, lds + 32768 + dstKB[i]);
      }
    }
  }

  float bv[4];
#pragma unroll
  for (int n = 0; n < 4; ++n) bv[n] = bias[bn + wn * 64 + n * 16 + li];

  // f32 + residual epilogue; per-wave 8KB region, reused per m (wave-private,
  // LDS ops within a wave execute in order -> WAR safe).
  float* wl = (float*)(lds + w * 8192);
#pragma unroll
  for (int m = 0; m < 8; ++m) {
#pragma unroll
    for (int n = 0; n < 4; ++n)
#pragma unroll
      for (int jj = 0; jj < 4; ++jj)
        wl[(lc * 4 + jj) * 68 + li + n * 16] = acc[m][n][jj] + bv[n];
#pragma unroll
    for (int i = 0; i < 4; ++i) {
      const int rr = i * 4 + lc;
      f32x4 vv = *(const f32x4*)(wl + rr * 68 + li * 4);
      const size_t gi = (size_t)(bm + wm * 128 + m * 16 + rr) * 1024
                      + bn + wn * 64 + li * 4;
      const u16x4 rv = *(const u16x4*)(res + gi);
      f32x4 ov;
#pragma unroll
      for (int jj = 0; jj < 4; ++jj) ov[jj] = vv[jj] + bf2f(rv[jj]);
      *(f32x4*)(Cout + gi) = ov;
    }
  }
}

// ---------------------------------------------------------------------------
// Attention core. qk8 chunk-blocked fp8, vbuf8 fp8; writes abuf8 fp8.
// ---------------------------------------------------------------------------
__global__ __launch_bounds__(256)
void attn_kernel(const unsigned char* __restrict__ qk8,
                 const unsigned char* __restrict__ vbuf8,
                 const float* __restrict__ lam_pre,
                 const float* __restrict__ L2b,
                 unsigned char* __restrict__ aout8)
{
  const int b = blockIdx.x;
  const int hd = threadIdx.x >> 6;
  const int lane = threadIdx.x & 63;
  const int g = lane >> 5;
  const int l5 = lane & 31;
  const size_t row = (size_t)(2 * b + g);

  const size_t cbase = (row >> 5) * 131072
                     + (size_t)(hd * 4 + (l5 >> 3)) * 2048
                     + (row & 31) * 64 + (l5 & 7) * 8;
  const uint2 p1 = *(const uint2*)(qk8 + cbase);
  const uint2 p2 = *(const uint2*)(qk8 + cbase + 32768);
  const uint2 p3 = *(const uint2*)(qk8 + cbase + 65536);
  const uint2 p4 = *(const uint2*)(qk8 + cbase + 98304);
  const uint2 pv = *(const uint2*)(vbuf8 + row * 1024 + hd * 256 + l5 * 8);

  float q1[8], k1[8], q2[8], k2[8], vf[8];
  dec8(p1, q1); dec8(p2, k1); dec8(p3, q2); dec8(p4, k2);
  dec8(pv, vf);

  float ss1 = 0.f, sc1 = 0.f, ss2 = 0.f, sc2 = 0.f;
#pragma unroll
  for (int j = 0; j < 8; ++j) {
    const float k1o = __shfl_xor(k1[j], 32, 64);
    const float k2o = __shfl_xor(k2[j], 32, 64);
    ss1 += q1[j] * k1[j]; sc1 += q1[j] * k1o;
    ss2 += q2[j] * k2[j]; sc2 += q2[j] * k2o;
  }
#pragma unroll
  for (int m = 16; m >= 1; m >>= 1) {
    ss1 += __shfl_xor(ss1, m, 64); sc1 += __shfl_xor(sc1, m, 64);
    ss2 += __shfl_xor(ss2, m, 64); sc2 += __shfl_xor(sc2, m, 64);
  }

  float e0 = ss1 * ATT_SCALE, e1 = sc1 * ATT_SCALE;
  float mx = fmaxf(e0, e1);
  float xs = expf(e0 - mx), xc = expf(e1 - mx);
  float inv = 1.f / (xs + xc);
  const float a1s = xs * inv, a1c = xc * inv;

  e0 = ss2 * ATT_SCALE; e1 = sc2 * ATT_SCALE;
  mx = fmaxf(e0, e1);
  xs = expf(e0 - mx); xc = expf(e1 - mx);
  inv = 1.f / (xs + xc);
  const float a2s = xs * inv, a2c = xc * inv;

  const float lm = 1.f / (1.f + expf(-(lam_pre[b] + L2b[0])));
  const float ps = fmaxf(a1s - lm * a2s, 0.f);
  const float pc = fmaxf(a1c - lm * a2c, 0.f);

  unsigned lo = 0, hi = 0;
#pragma unroll
  for (int j = 0; j < 4; ++j) {
    const float vo = __shfl_xor(vf[j], 32, 64);
    lo |= (unsigned)cvt1_fp8(ps * vf[j] + pc * vo) << (8 * j);
  }
#pragma unroll
  for (int j = 4; j < 8; ++j) {
    const float vo = __shfl_xor(vf[j], 32, 64);
    hi |= (unsigned)cvt1_fp8(ps * vf[j] + pc * vo) << (8 * (j - 4));
  }
  uint2 o2; o2.x = lo; o2.y = hi;
  *(uint2*)(aout8 + row * 1024 + hd * 256 + l5 * 8) = o2;
}

// ---------------------------------------------------------------------------
// Fused prep: z 0-4 -> qw8 fp8 (Q1,K1,Q2,K2,V), z 5 -> wot8 fp8,
// z 6-21 x -> x_bf + x_f8, z 22 L1 transpose, z 23 bias concat + lamp zero.
// ---------------------------------------------------------------------------
__global__ void prep_k(const float* __restrict__ s0, const float* __restrict__ s1,
                       const float* __restrict__ s2, const float* __restrict__ s3,
                       const float* __restrict__ s4, const float* __restrict__ s5,
                       const float* __restrict__ L1w,
                       const float* __restrict__ b0, const float* __restrict__ b1,
                       const float* __restrict__ b2, const float* __restrict__ b3,
                       const float* __restrict__ b4,
                       const float* __restrict__ x,
                       unsigned char* __restrict__ qw8,
                       unsigned char* __restrict__ wot8,
                       unsigned short* __restrict__ l1t,
                       float* __restrict__ bcat,
                       unsigned short* __restrict__ x_bf,
                       unsigned char* __restrict__ x_f8,
                       float* __restrict__ lamp)
{
  __shared__ float tile[32][33];
  const int z = blockIdx.z;
  const int tx = threadIdx.x, ty = threadIdx.y;

  if (z < 6) {
    const float* W;
    switch (z) {
      case 0: W = s0; break;
      case 1: W = s1; break;
      case 2: W = s2; break;
      case 3: W = s3; break;
      case 4: W = s4; break;
      default: W = s5; break;
    }
    const int bn = blockIdx.x * 32, bk = blockIdx.y * 32;
#pragma unroll
    for (int i = ty; i < 32; i += 8)
      tile[i][tx] = W[(size_t)(bk + i) * 1024 + bn + tx];
    __syncthreads();
    unsigned char* Wt = (z < 5) ? (qw8 + (size_t)z * 1048576) : wot8;
#pragma unroll
    for (int i = ty; i < 32; i += 8)
      Wt[(size_t)(bn + i) * 1024 + bk + tx] = cvt1_fp8(tile[tx][i]);
    return;
  }
  if (z < 22) {
    const int c = (z - 6) * 1024 + blockIdx.y * 32 + blockIdx.x;
    const int i = c * 256 + ty * 32 + tx;
    const float4* p = (const float4*)x + (size_t)i * 2;
    float4 a = p[0], b = p[1];
    float f[8] = {a.x, a.y, a.z, a.w, b.x, b.y, b.z, b.w};
    u16x8 v; unsigned lo = 0, hi = 0;
#pragma unroll
    for (int j = 0; j < 8; ++j) v[j] = f2bf(f[j]);
#pragma unroll
    for (int j = 0; j < 4; ++j) lo |= (unsigned)cvt1_fp8(f[j]) << (8 * j);
#pragma unroll
    for (int j = 0; j < 4; ++j) hi |= (unsigned)cvt1_fp8(f[4 + j]) << (8 * j);
    *(u16x8*)(x_bf + (size_t)i * 8) = v;
    uint2 c8; c8.x = lo; c8.y = hi;
    *(uint2*)(x_f8 + (size_t)i * 8) = c8;
    return;
  }
  if (z == 22) {
    const int idx = blockIdx.y * 32 + blockIdx.x;
    if (idx >= 512) return;
    const int bn = (idx & 7) * 32, bk = (idx >> 3) * 32;
#pragma unroll
    for (int i = ty; i < 32; i += 8)
      tile[i][tx] = L1w[(size_t)(bk + i) * 256 + bn + tx];
    __syncthreads();
#pragma unroll
    for (int i = ty; i < 32; i += 8)
      l1t[(size_t)(bn + i) * 2048 + bk + tx] = f2bf(tile[tx][i]);
    return;
  }
  const int idx = blockIdx.y * 32 + blockIdx.x;
  const int t = ty * 32 + tx;
  if (idx < 20) {
    const int i = idx * 256 + t;
    const float* src;
    switch (i >> 10) {
      case 0: src = b0; break;
      case 1: src = b1; break;
      case 2: src = b2; break;
      case 3: src = b3; break;
      default: src = b4; break;
    }
    bcat[i] = src[i & 1023];
  } else if (idx < 84) {
    lamp[(idx - 20) * 256 + t] = 0.f;
  }
}

// ---------------------------------------------------------------------------
extern "C" void kernel_launch(void* const* d_in, const int* in_sizes, int n_in,
                              void* d_out, int out_size, void* d_ws, size_t ws_size,
                              hipStream_t stream)
{
  const float* x    = (const float*)d_in[0];
  const float* WQ1w = (const float*)d_in[1];  const float* WQ1b = (const float*)d_in[2];
  const float* WK1w = (const float*)d_in[3];  const float* WK1b = (const float*)d_in[4];
  const float* WQ2w = (const float*)d_in[5];  const float* WQ2b = (const float*)d_in[6];
  const float* WK2w = (const float*)d_in[7];  const float* WK2b = (const float*)d_in[8];
  const float* WVw  = (const float*)d_in[9];  const float* WVb  = (const float*)d_in[10];
  const float* WOw  = (const float*)d_in[11]; const float* WOb  = (const float*)d_in[12];
  const float* L1w  = (const float*)d_in[13]; const float* L1b  = (const float*)d_in[14];
  const float* L2w  = (const float*)d_in[15]; const float* L2b  = (const float*)d_in[16];

  char* ws = (char*)d_ws;
  size_t off = 0;
  unsigned short* x_bf  = (unsigned short*)(ws + off); off += (size_t)33554432 * 2;  // 64MB
  unsigned char*  x_f8  = (unsigned char*)(ws + off);  off += (size_t)33554432;      // 32MB
  unsigned char*  qw8   = (unsigned char*)(ws + off);  off += (size_t)5242880;       // 5MB
  unsigned char*  wot8  = (unsigned char*)(ws + off);  off += (size_t)1048576;       // 1MB
  unsigned short* l1t   = (unsigned short*)(ws + off); off += (size_t)524288 * 2;    // 1MB
  float*          bcat  = (float*)(ws + off);          off += (size_t)5120 * 4;
  unsigned char*  qk8   = (unsigned char*)(ws + off);  off += (size_t)32768 * 4096;  // 128MB
  unsigned char*  vbuf8 = (unsigned char*)(ws + off);  off += (size_t)33554432;      // 32MB
  unsigned char*  abuf8 = (unsigned char*)(ws + off);  off += (size_t)33554432;      // 32MB
  float*          lamp  = (float*)(ws + off);          off += (size_t)16384 * 4;

  // fused prep
  prep_k<<<dim3(32, 32, 24), dim3(32, 8), 0, stream>>>(
      WQ1w, WK1w, WQ2w, WK2w, WVw, WOw, L1w,
      WQ1b, WK1b, WQ2b, WK2b, WVb, x,
      qw8, wot8, l1t, bcat, x_bf, x_f8, lamp);

  // MX projections (QK fp8 + V fp8 out) + fused lambda (blocks 0-127)
  gemm_mx<<<dim3(128 + 2560), 512, 0, stream>>>(
      x_f8, qw8, bcat, qk8, vbuf8, 20, x_bf, l1t, L1b, L2w, lamp);

  // attention core -> abuf8 (fp8)
  attn_kernel<<<16384, 256, 0, stream>>>(qk8, vbuf8, lamp, L2b, abuf8);

  // output: MX-fp8 abuf8 @ wot8 + bias + residual(x_bf), f32
  gemm_womx<<<dim3(512), 512, 0, stream>>>(
      abuf8, wot8, WOb, (float*)d_out, x_bf);
}

// Round 20
// 430.771 us; speedup vs baseline: 4.4337x; 4.4337x over previous
//
#include <hip/hip_runtime.h>
#include <stdint.h>

// ---------------------------------------------------------------------------
// AdaptiveDiffAttention on MI355X (gfx950)
// Round 20 (= r19 with launch_bounds fixed): 256x256 MX tile, single 64KB LDS
// buffer, __launch_bounds__(512, 2) -> compiler free to use ~124 VGPR; if
// <=128 the HW schedules 4 waves/SIMD = 2 blocks/CU (LDS fits 2x64KB).
// r19's (512,4) forced 64 VGPR -> acc spilled (7.3GB scratch traffic).
// Numerics = r17 (absmax 0.0859 verified).
// ---------------------------------------------------------------------------

#define ATT_SCALE 0.0625f // 256^-0.5

typedef __attribute__((ext_vector_type(8)))  short   s16x8;
typedef __attribute__((ext_vector_type(4)))  float   f32x4;
typedef __attribute__((ext_vector_type(2)))  float   f32x2;
typedef __attribute__((ext_vector_type(8)))  int     i32x8;
typedef __attribute__((ext_vector_type(8)))  unsigned short u16x8;
typedef __attribute__((ext_vector_type(4)))  unsigned short u16x4;

__device__ __forceinline__ unsigned short f2bf(float f) {
  unsigned u = __float_as_uint(f);
  u += 0x7FFFu + ((u >> 16) & 1u);   // RNE
  return (unsigned short)(u >> 16);
}
__device__ __forceinline__ float bf2f(unsigned short s) {
  return __uint_as_float((unsigned)s << 16);
}

__device__ __forceinline__ unsigned char f2e4m3(float f) {
  unsigned u = __float_as_uint(f);
  unsigned s = (u >> 24) & 0x80u;
  float a = fabsf(f);
  if (a >= 448.f) return (unsigned char)(s | 0x7E);
  if (a < 0.0009765625f) return (unsigned char)s;
  int e = (int)((u >> 23) & 0xFF) - 127;
  if (e < -6) {
    int q = (int)rintf(a * 512.f);
    if (q >= 8) return (unsigned char)(s | 0x08);
    return (unsigned char)(s | q);
  }
  unsigned mant = u & 0x7FFFFFu;
  unsigned mr = mant + 0x7FFFFu + ((mant >> 20) & 1u);
  e += (int)(mr >> 23);
  mant = (mr >> 20) & 7u;
  if (e > 8) return (unsigned char)(s | 0x7E);
  return (unsigned char)(s | ((e + 7) << 3) | mant);
}
__device__ __forceinline__ float e4m3f(unsigned v) {
  unsigned e = (v >> 3) & 15u, m = v & 7u;
  float mag = (e == 0) ? (float)m * 0.001953125f
                       : __uint_as_float(((e + 120u) << 23) | (m << 20));
  return (v & 0x80u) ? -mag : mag;
}

__device__ __forceinline__ unsigned char cvt1_fp8(float v) {
#if __has_builtin(__builtin_amdgcn_cvt_pk_fp8_f32)
  return (unsigned char)(__builtin_amdgcn_cvt_pk_fp8_f32(v, v, 0, false) & 0xff);
#else
  return f2e4m3(v);
#endif
}

__device__ __forceinline__ void dec8(uint2 p, float* o) {
#if __has_builtin(__builtin_amdgcn_cvt_pk_f32_fp8)
  f32x2 a = __builtin_amdgcn_cvt_pk_f32_fp8((int)p.x, false);
  f32x2 b = __builtin_amdgcn_cvt_pk_f32_fp8((int)p.x, true);
  f32x2 c = __builtin_amdgcn_cvt_pk_f32_fp8((int)p.y, false);
  f32x2 d = __builtin_amdgcn_cvt_pk_f32_fp8((int)p.y, true);
  o[0] = a[0]; o[1] = a[1]; o[2] = b[0]; o[3] = b[1];
  o[4] = c[0]; o[5] = c[1]; o[6] = d[0]; o[7] = d[1];
#else
#pragma unroll
  for (int j = 0; j < 4; ++j) o[j]     = e4m3f((p.x >> (8 * j)) & 255u);
#pragma unroll
  for (int j = 0; j < 4; ++j) o[4 + j] = e4m3f((p.y >> (8 * j)) & 255u);
#endif
}

__device__ __forceinline__ void async16(const void* g, void* l) {
  __builtin_amdgcn_global_load_lds((__attribute__((address_space(1))) void*)g,
                                   (__attribute__((address_space(3))) void*)l,
                                   16, 0, 0);
}

// ---------------------------------------------------------------------------
// MX-fp8 proj GEMM + fused lambda. 512 threads, 64KB LDS.
// Blocks 0..127: lambda. Blocks 128+: [32768,1024]fp8 @ [5120,1024]^T fp8,
// 256x256 tile, BK=128, single buffer.
// ---------------------------------------------------------------------------
__global__ __launch_bounds__(512, 2)
void gemm_mx(const unsigned char* __restrict__ A,
             const unsigned char* __restrict__ Bt,
             const float* __restrict__ bias,
             unsigned char* __restrict__ Cout,
             unsigned char* __restrict__ Vout,
             int NN,
             const unsigned short* __restrict__ xbf,
             const unsigned short* __restrict__ lamBt,
             const float* __restrict__ lamL1b,
             const float* __restrict__ lamL2w,
             float* __restrict__ lamp)
{
  __shared__ __align__(16) char lds[65536];
  const int tid  = threadIdx.x;
  const int lane = tid & 63, w = tid >> 6;
  const int wm = w >> 2, wn = w & 3;
  const int li = lane & 15, lc = lane >> 4;

  if (blockIdx.x < 128) {
    // ---- fused lambda block (r12-proven) ----
    const int bm_l = blockIdx.x * 128;
    const int t = tid;
    const size_t aSrc  = (size_t)(bm_l + (t >> 2)) * 2048 + (t & 3) * 8;
    const size_t b0Src = (size_t)(t >> 2) * 2048 + (t & 3) * 8;
    const size_t b1Src = (size_t)(128 + (t >> 2)) * 2048 + (t & 3) * 8;

    f32x4 acc[4][4];
#pragma unroll
    for (int i = 0; i < 4; ++i)
#pragma unroll
      for (int j = 0; j < 4; ++j) acc[i][j] = (f32x4)0.f;

    for (int k0 = 0; k0 < 2048; k0 += 32) {
      async16(xbf   + aSrc  + k0, lds + w * 1024);
      async16(lamBt + b0Src + k0, lds + 8192 + w * 1024);
      async16(lamBt + b1Src + k0, lds + 16384 + w * 1024);
      __syncthreads();
      s16x8 aR[4], bR[4];
#pragma unroll
      for (int m = 0; m < 4; ++m)
        aR[m] = *(const s16x8*)(lds + ((w >> 2) * 64 + m * 16 + li) * 64 + lc * 16);
#pragma unroll
      for (int n = 0; n < 4; ++n)
        bR[n] = *(const s16x8*)(lds + 8192 + ((w & 3) * 64 + n * 16 + li) * 64 + lc * 16);
#pragma unroll
      for (int m = 0; m < 4; ++m)
#pragma unroll
        for (int n = 0; n < 4; ++n)
          acc[m][n] = __builtin_amdgcn_mfma_f32_16x16x32_bf16(aR[m], bR[n], acc[m][n], 0, 0, 0);
      __syncthreads();
    }

    float l2v[4], bvv[4];
#pragma unroll
    for (int n = 0; n < 4; ++n) {
      const int col = (w & 3) * 64 + n * 16 + li;
      l2v[n] = lamL2w[col];
      bvv[n] = lamL1b[col];
    }
#pragma unroll
    for (int m = 0; m < 4; ++m)
#pragma unroll
      for (int j = 0; j < 4; ++j) {
        float part = 0.f;
#pragma unroll
        for (int n = 0; n < 4; ++n)
          part += fmaxf(acc[m][n][j] + bvv[n], 0.f) * l2v[n];
        part += __shfl_xor(part, 1, 64);
        part += __shfl_xor(part, 2, 64);
        part += __shfl_xor(part, 4, 64);
        part += __shfl_xor(part, 8, 64);
        if ((lane & 15) == 0)
          atomicAdd(lamp + bm_l + (w >> 2) * 64 + m * 16 + lc * 4 + j, part);
      }
    return;
  }

  // ---- MX proj path: 256x256 tile, single 64KB buffer ----
  const int bid = blockIdx.x - 128;
  const int nwg = 2560;
  const int swz = (bid & 7) * (nwg >> 3) + (bid >> 3);
  const int bm = (swz / NN) * 256;
  const int bn = (swz % NN) * 256;

  const int grow   = lane >> 3;
  const int gchunk = ((lane & 7) ^ grow) * 16;
  size_t aSrc[4], bSrc[4];
  int dstKB[4];
#pragma unroll
  for (int i = 0; i < 4; ++i) {
    const int rr = (i * 8 + w) * 8 + grow;
    aSrc[i] = (size_t)(bm + rr) * 1024 + gchunk;
    bSrc[i] = (size_t)(bn + rr) * 1024 + gchunk;
    dstKB[i] = (i * 8 + w) * 1024;
  }

  const int x7   = li & 7;
  const int off0 = ((2 * lc)     ^ x7) * 16;
  const int off1 = ((2 * lc + 1) ^ x7) * 16;
  const int aRow = (wm * 128 + li) * 128;
  const int bRow = 32768 + (wn * 64 + li) * 128;

  f32x4 acc[8][4];
#pragma unroll
  for (int m = 0; m < 8; ++m)
#pragma unroll
    for (int n = 0; n < 4; ++n) acc[m][n] = (f32x4)0.f;

  // stage tile 0
#pragma unroll
  for (int i = 0; i < 4; ++i) {
    async16(A  + aSrc[i], lds + dstKB[i]);
    async16(Bt + bSrc[i], lds + 32768 + dstKB[i]);
  }

  for (int t = 0; t < 8; ++t) {
    asm volatile("s_waitcnt vmcnt(0)" ::: "memory");
    __builtin_amdgcn_s_barrier();

    i32x8 bF[4];
#pragma unroll
    for (int nf = 0; nf < 4; ++nf) {
      const char* p = lds + bRow + nf * 2048;
      uint4* bp = (uint4*)&bF[nf];
      bp[0] = *(const uint4*)(p + off0);
      bp[1] = *(const uint4*)(p + off1);
    }
#pragma unroll
    for (int mh = 0; mh < 2; ++mh) {
      i32x8 aF[4];
#pragma unroll
      for (int mf = 0; mf < 4; ++mf) {
        const char* p = lds + aRow + (mh * 4 + mf) * 2048;
        uint4* ap = (uint4*)&aF[mf];
        ap[0] = *(const uint4*)(p + off0);
        ap[1] = *(const uint4*)(p + off1);
      }
      __builtin_amdgcn_s_setprio(1);
#pragma unroll
      for (int mf = 0; mf < 4; ++mf)
#pragma unroll
        for (int nf = 0; nf < 4; ++nf)
          acc[mh * 4 + mf][nf] = __builtin_amdgcn_mfma_scale_f32_16x16x128_f8f6f4(
              aF[mf], bF[nf], acc[mh * 4 + mf][nf],
              0, 0, 0, 0x7F7F7F7F, 0, 0x7F7F7F7F);
      __builtin_amdgcn_s_setprio(0);
    }
    __builtin_amdgcn_s_barrier();
    if (t < 7) {
      const size_t kt = (size_t)(t + 1) * 128;
#pragma unroll
      for (int i = 0; i < 4; ++i) {
        async16(A  + aSrc[i] + kt, lds + dstKB[i]);
        async16(Bt + bSrc[i] + kt, lds + 32768 + dstKB[i]);
      }
    }
  }

  float bv[4];
#pragma unroll
  for (int n = 0; n < 4; ++n) bv[n] = bias[bn + wn * 64 + n * 16 + li];

  if (bn < 4096) {
    // fp8 chunk-blocked epilogue -> qk8, packed dword LDS writes.
    unsigned char* wl0 = (unsigned char*)(lds + w * 8192);
#pragma unroll
    for (int mp = 0; mp < 4; ++mp) {
      unsigned char* wl = wl0 + (mp & 1) * 2560;
#pragma unroll
      for (int mi = 0; mi < 2; ++mi)
#pragma unroll
        for (int jj = 0; jj < 4; ++jj) {
          unsigned d = 0;
#pragma unroll
          for (int n = 0; n < 4; ++n) {
            float v = acc[mp * 2 + mi][n][jj] + bv[n];
            d |= (unsigned)cvt1_fp8(v) << (8 * n);
          }
          *(unsigned*)(wl + (mi * 16 + lc * 4 + jj) * 80 + li * 4) = d;
        }
      const size_t base = (size_t)((bm + wm * 128 + mp * 32) >> 5) * 131072
                        + (size_t)((bn >> 6) + wn) * 2048;
      uint4 v0 = *(const uint4*)(wl + (lane >> 2) * 80 + (lane & 3) * 16);
      *(uint4*)(Cout + base + lane * 16) = v0;
      uint4 v1 = *(const uint4*)(wl + (16 + (lane >> 2)) * 80 + (lane & 3) * 16);
      *(uint4*)(Cout + base + 1024 + lane * 16) = v1;
    }
  } else {
    // fp8 epilogue -> vbuf8 [.,1024] row-major
    unsigned char* wl0 = (unsigned char*)(lds + w * 8192);
    const int cb = bn - 4096;
#pragma unroll
    for (int mp = 0; mp < 4; ++mp) {
      unsigned char* wl = wl0 + (mp & 1) * 2560;
#pragma unroll
      for (int mi = 0; mi < 2; ++mi)
#pragma unroll
        for (int n = 0; n < 4; ++n)
#pragma unroll
          for (int jj = 0; jj < 4; ++jj) {
            float v = acc[mp * 2 + mi][n][jj] + bv[n];
            wl[(mi * 16 + lc * 4 + jj) * 72 + n * 16 + li] = cvt1_fp8(v);
          }
#pragma unroll
      for (int i = 0; i < 4; ++i) {
        const int rr = i * 8 + (lane >> 3);
        uint2 vv = *(const uint2*)(wl + rr * 72 + (lane & 7) * 8);
        const size_t gi = (size_t)(bm + wm * 128 + mp * 32 + rr) * 1024
                        + cb + wn * 64 + (lane & 7) * 8;
        *(uint2*)(Vout + gi) = vv;
      }
    }
  }
}

// ---------------------------------------------------------------------------
// MX-fp8 WO GEMM: out[32768,1024](f32) = abuf8 @ wot8^T + WOb + res(bf16).
// 256x256 tile, single 64KB buffer.
// ---------------------------------------------------------------------------
__global__ __launch_bounds__(512, 2)
void gemm_womx(const unsigned char* __restrict__ A,
               const unsigned char* __restrict__ Bt,
               const float* __restrict__ bias,
               float* __restrict__ Cout,
               const unsigned short* __restrict__ res)
{
  __shared__ __align__(16) char lds[65536];
  const int tid  = threadIdx.x;
  const int lane = tid & 63, w = tid >> 6;
  const int wm = w >> 2, wn = w & 3;
  const int li = lane & 15, lc = lane >> 4;

  const int swz = (blockIdx.x & 7) * 64 + (blockIdx.x >> 3);
  const int bm = (swz >> 2) * 256;
  const int bn = (swz & 3) * 256;

  const int grow   = lane >> 3;
  const int gchunk = ((lane & 7) ^ grow) * 16;
  size_t aSrc[4], bSrc[4];
  int dstKB[4];
#pragma unroll
  for (int i = 0; i < 4; ++i) {
    const int rr = (i * 8 + w) * 8 + grow;
    aSrc[i] = (size_t)(bm + rr) * 1024 + gchunk;
    bSrc[i] = (size_t)(bn + rr) * 1024 + gchunk;
    dstKB[i] = (i * 8 + w) * 1024;
  }

  const int x7   = li & 7;
  const int off0 = ((2 * lc)     ^ x7) * 16;
  const int off1 = ((2 * lc + 1) ^ x7) * 16;
  const int aRow = (wm * 128 + li) * 128;
  const int bRow = 32768 + (wn * 64 + li) * 128;

  f32x4 acc[8][4];
#pragma unroll
  for (int m = 0; m < 8; ++m)
#pragma unroll
    for (int n = 0; n < 4; ++n) acc[m][n] = (f32x4)0.f;

#pragma unroll
  for (int i = 0; i < 4; ++i) {
    async16(A  + aSrc[i], lds + dstKB[i]);
    async16(Bt + bSrc[i], lds + 32768 + dstKB[i]);
  }

  for (int t = 0; t < 8; ++t) {
    asm volatile("s_waitcnt vmcnt(0)" ::: "memory");
    __builtin_amdgcn_s_barrier();

    i32x8 bF[4];
#pragma unroll
    for (int nf = 0; nf < 4; ++nf) {
      const char* p = lds + bRow + nf * 2048;
      uint4* bp = (uint4*)&bF[nf];
      bp[0] = *(const uint4*)(p + off0);
      bp[1] = *(const uint4*)(p + off1);
    }
#pragma unroll
    for (int mh = 0; mh < 2; ++mh) {
      i32x8 aF[4];
#pragma unroll
      for (int mf = 0; mf < 4; ++mf) {
        const char* p = lds + aRow + (mh * 4 + mf) * 2048;
        uint4* ap = (uint4*)&aF[mf];
        ap[0] = *(const uint4*)(p + off0);
        ap[1] = *(const uint4*)(p + off1);
      }
      __builtin_amdgcn_s_setprio(1);
#pragma unroll
      for (int mf = 0; mf < 4; ++mf)
#pragma unroll
        for (int nf = 0; nf < 4; ++nf)
          acc[mh * 4 + mf][nf] = __builtin_amdgcn_mfma_scale_f32_16x16x128_f8f6f4(
              aF[mf], bF[nf], acc[mh * 4 + mf][nf],
              0, 0, 0, 0x7F7F7F7F, 0, 0x7F7F7F7F);
      __builtin_amdgcn_s_setprio(0);
    }
    __builtin_amdgcn_s_barrier();
    if (t < 7) {
      const size_t kt = (size_t)(t + 1) * 128;
#pragma unroll
      for (int i = 0; i < 4; ++i) {
        async16(A  + aSrc[i] + kt, lds + dstKB[i]);
        async16(Bt + bSrc[i] + kt, lds + 32768 + dstKB[i]);
      }
    }
  }

  float bv[4];
#pragma unroll
  for (int n = 0; n < 4; ++n) bv[n] = bias[bn + wn * 64 + n * 16 + li];

  // f32 + residual epilogue; per-wave 8KB region, reused per m (wave-private,
  // LDS ops within a wave execute in order -> WAR safe).
  float* wl = (float*)(lds + w * 8192);
#pragma unroll
  for (int m = 0; m < 8; ++m) {
#pragma unroll
    for (int n = 0; n < 4; ++n)
#pragma unroll
      for (int jj = 0; jj < 4; ++jj)
        wl[(lc * 4 + jj) * 68 + li + n * 16] = acc[m][n][jj] + bv[n];
#pragma unroll
    for (int i = 0; i < 4; ++i) {
      const int rr = i * 4 + lc;
      f32x4 vv = *(const f32x4*)(wl + rr * 68 + li * 4);
      const size_t gi = (size_t)(bm + wm * 128 + m * 16 + rr) * 1024
                      + bn + wn * 64 + li * 4;
      const u16x4 rv = *(const u16x4*)(res + gi);
      f32x4 ov;
#pragma unroll
      for (int jj = 0; jj < 4; ++jj) ov[jj] = vv[jj] + bf2f(rv[jj]);
      *(f32x4*)(Cout + gi) = ov;
    }
  }
}

// ---------------------------------------------------------------------------
// Attention core. qk8 chunk-blocked fp8, vbuf8 fp8; writes abuf8 fp8.
// ---------------------------------------------------------------------------
__global__ __launch_bounds__(256)
void attn_kernel(const unsigned char* __restrict__ qk8,
                 const unsigned char* __restrict__ vbuf8,
                 const float* __restrict__ lam_pre,
                 const float* __restrict__ L2b,
                 unsigned char* __restrict__ aout8)
{
  const int b = blockIdx.x;
  const int hd = threadIdx.x >> 6;
  const int lane = threadIdx.x & 63;
  const int g = lane >> 5;
  const int l5 = lane & 31;
  const size_t row = (size_t)(2 * b + g);

  const size_t cbase = (row >> 5) * 131072
                     + (size_t)(hd * 4 + (l5 >> 3)) * 2048
                     + (row & 31) * 64 + (l5 & 7) * 8;
  const uint2 p1 = *(const uint2*)(qk8 + cbase);
  const uint2 p2 = *(const uint2*)(qk8 + cbase + 32768);
  const uint2 p3 = *(const uint2*)(qk8 + cbase + 65536);
  const uint2 p4 = *(const uint2*)(qk8 + cbase + 98304);
  const uint2 pv = *(const uint2*)(vbuf8 + row * 1024 + hd * 256 + l5 * 8);

  float q1[8], k1[8], q2[8], k2[8], vf[8];
  dec8(p1, q1); dec8(p2, k1); dec8(p3, q2); dec8(p4, k2);
  dec8(pv, vf);

  float ss1 = 0.f, sc1 = 0.f, ss2 = 0.f, sc2 = 0.f;
#pragma unroll
  for (int j = 0; j < 8; ++j) {
    const float k1o = __shfl_xor(k1[j], 32, 64);
    const float k2o = __shfl_xor(k2[j], 32, 64);
    ss1 += q1[j] * k1[j]; sc1 += q1[j] * k1o;
    ss2 += q2[j] * k2[j]; sc2 += q2[j] * k2o;
  }
#pragma unroll
  for (int m = 16; m >= 1; m >>= 1) {
    ss1 += __shfl_xor(ss1, m, 64); sc1 += __shfl_xor(sc1, m, 64);
    ss2 += __shfl_xor(ss2, m, 64); sc2 += __shfl_xor(sc2, m, 64);
  }

  float e0 = ss1 * ATT_SCALE, e1 = sc1 * ATT_SCALE;
  float mx = fmaxf(e0, e1);
  float xs = expf(e0 - mx), xc = expf(e1 - mx);
  float inv = 1.f / (xs + xc);
  const float a1s = xs * inv, a1c = xc * inv;

  e0 = ss2 * ATT_SCALE; e1 = sc2 * ATT_SCALE;
  mx = fmaxf(e0, e1);
  xs = expf(e0 - mx); xc = expf(e1 - mx);
  inv = 1.f / (xs + xc);
  const float a2s = xs * inv, a2c = xc * inv;

  const float lm = 1.f / (1.f + expf(-(lam_pre[b] + L2b[0])));
  const float ps = fmaxf(a1s - lm * a2s, 0.f);
  const float pc = fmaxf(a1c - lm * a2c, 0.f);

  unsigned lo = 0, hi = 0;
#pragma unroll
  for (int j = 0; j < 4; ++j) {
    const float vo = __shfl_xor(vf[j], 32, 64);
    lo |= (unsigned)cvt1_fp8(ps * vf[j] + pc * vo) << (8 * j);
  }
#pragma unroll
  for (int j = 4; j < 8; ++j) {
    const float vo = __shfl_xor(vf[j], 32, 64);
    hi |= (unsigned)cvt1_fp8(ps * vf[j] + pc * vo) << (8 * (j - 4));
  }
  uint2 o2; o2.x = lo; o2.y = hi;
  *(uint2*)(aout8 + row * 1024 + hd * 256 + l5 * 8) = o2;
}

// ---------------------------------------------------------------------------
// Fused prep: z 0-4 -> qw8 fp8 (Q1,K1,Q2,K2,V), z 5 -> wot8 fp8,
// z 6-21 x -> x_bf + x_f8, z 22 L1 transpose, z 23 bias concat + lamp zero.
// ---------------------------------------------------------------------------
__global__ void prep_k(const float* __restrict__ s0, const float* __restrict__ s1,
                       const float* __restrict__ s2, const float* __restrict__ s3,
                       const float* __restrict__ s4, const float* __restrict__ s5,
                       const float* __restrict__ L1w,
                       const float* __restrict__ b0, const float* __restrict__ b1,
                       const float* __restrict__ b2, const float* __restrict__ b3,
                       const float* __restrict__ b4,
                       const float* __restrict__ x,
                       unsigned char* __restrict__ qw8,
                       unsigned char* __restrict__ wot8,
                       unsigned short* __restrict__ l1t,
                       float* __restrict__ bcat,
                       unsigned short* __restrict__ x_bf,
                       unsigned char* __restrict__ x_f8,
                       float* __restrict__ lamp)
{
  __shared__ float tile[32][33];
  const int z = blockIdx.z;
  const int tx = threadIdx.x, ty = threadIdx.y;

  if (z < 6) {
    const float* W;
    switch (z) {
      case 0: W = s0; break;
      case 1: W = s1; break;
      case 2: W = s2; break;
      case 3: W = s3; break;
      case 4: W = s4; break;
      default: W = s5; break;
    }
    const int bn = blockIdx.x * 32, bk = blockIdx.y * 32;
#pragma unroll
    for (int i = ty; i < 32; i += 8)
      tile[i][tx] = W[(size_t)(bk + i) * 1024 + bn + tx];
    __syncthreads();
    unsigned char* Wt = (z < 5) ? (qw8 + (size_t)z * 1048576) : wot8;
#pragma unroll
    for (int i = ty; i < 32; i += 8)
      Wt[(size_t)(bn + i) * 1024 + bk + tx] = cvt1_fp8(tile[tx][i]);
    return;
  }
  if (z < 22) {
    const int c = (z - 6) * 1024 + blockIdx.y * 32 + blockIdx.x;
    const int i = c * 256 + ty * 32 + tx;
    const float4* p = (const float4*)x + (size_t)i * 2;
    float4 a = p[0], b = p[1];
    float f[8] = {a.x, a.y, a.z, a.w, b.x, b.y, b.z, b.w};
    u16x8 v; unsigned lo = 0, hi = 0;
#pragma unroll
    for (int j = 0; j < 8; ++j) v[j] = f2bf(f[j]);
#pragma unroll
    for (int j = 0; j < 4; ++j) lo |= (unsigned)cvt1_fp8(f[j]) << (8 * j);
#pragma unroll
    for (int j = 0; j < 4; ++j) hi |= (unsigned)cvt1_fp8(f[4 + j]) << (8 * j);
    *(u16x8*)(x_bf + (size_t)i * 8) = v;
    uint2 c8; c8.x = lo; c8.y = hi;
    *(uint2*)(x_f8 + (size_t)i * 8) = c8;
    return;
  }
  if (z == 22) {
    const int idx = blockIdx.y * 32 + blockIdx.x;
    if (idx >= 512) return;
    const int bn = (idx & 7) * 32, bk = (idx >> 3) * 32;
#pragma unroll
    for (int i = ty; i < 32; i += 8)
      tile[i][tx] = L1w[(size_t)(bk + i) * 256 + bn + tx];
    __syncthreads();
#pragma unroll
    for (int i = ty; i < 32; i += 8)
      l1t[(size_t)(bn + i) * 2048 + bk + tx] = f2bf(tile[tx][i]);
    return;
  }
  const int idx = blockIdx.y * 32 + blockIdx.x;
  const int t = ty * 32 + tx;
  if (idx < 20) {
    const int i = idx * 256 + t;
    const float* src;
    switch (i >> 10) {
      case 0: src = b0; break;
      case 1: src = b1; break;
      case 2: src = b2; break;
      case 3: src = b3; break;
      default: src = b4; break;
    }
    bcat[i] = src[i & 1023];
  } else if (idx < 84) {
    lamp[(idx - 20) * 256 + t] = 0.f;
  }
}

// ---------------------------------------------------------------------------
extern "C" void kernel_launch(void* const* d_in, const int* in_sizes, int n_in,
                              void* d_out, int out_size, void* d_ws, size_t ws_size,
                              hipStream_t stream)
{
  const float* x    = (const float*)d_in[0];
  const float* WQ1w = (const float*)d_in[1];  const float* WQ1b = (const float*)d_in[2];
  const float* WK1w = (const float*)d_in[3];  const float* WK1b = (const float*)d_in[4];
  const float* WQ2w = (const float*)d_in[5];  const float* WQ2b = (const float*)d_in[6];
  const float* WK2w = (const float*)d_in[7];  const float* WK2b = (const float*)d_in[8];
  const float* WVw  = (const float*)d_in[9];  const float* WVb  = (const float*)d_in[10];
  const float* WOw  = (const float*)d_in[11]; const float* WOb  = (const float*)d_in[12];
  const float* L1w  = (const float*)d_in[13]; const float* L1b  = (const float*)d_in[14];
  const float* L2w  = (const float*)d_in[15]; const float* L2b  = (const float*)d_in[16];

  char* ws = (char*)d_ws;
  size_t off = 0;
  unsigned short* x_bf  = (unsigned short*)(ws + off); off += (size_t)33554432 * 2;  // 64MB
  unsigned char*  x_f8  = (unsigned char*)(ws + off);  off += (size_t)33554432;      // 32MB
  unsigned char*  qw8   = (unsigned char*)(ws + off);  off += (size_t)5242880;       // 5MB
  unsigned char*  wot8  = (unsigned char*)(ws + off);  off += (size_t)1048576;       // 1MB
  unsigned short* l1t   = (unsigned short*)(ws + off); off += (size_t)524288 * 2;    // 1MB
  float*          bcat  = (float*)(ws + off);          off += (size_t)5120 * 4;
  unsigned char*  qk8   = (unsigned char*)(ws + off);  off += (size_t)32768 * 4096;  // 128MB
  unsigned char*  vbuf8 = (unsigned char*)(ws + off);  off += (size_t)33554432;      // 32MB
  unsigned char*  abuf8 = (unsigned char*)(ws + off);  off += (size_t)33554432;      // 32MB
  float*          lamp  = (float*)(ws + off);          off += (size_t)16384 * 4;

  // fused prep
  prep_k<<<dim3(32, 32, 24), dim3(32, 8), 0, stream>>>(
      WQ1w, WK1w, WQ2w, WK2w, WVw, WOw, L1w,
      WQ1b, WK1b, WQ2b, WK2b, WVb, x,
      qw8, wot8, l1t, bcat, x_bf, x_f8, lamp);

  // MX projections (QK fp8 + V fp8 out) + fused lambda (blocks 0-127)
  gemm_mx<<<dim3(128 + 2560), 512, 0, stream>>>(
      x_f8, qw8, bcat, qk8, vbuf8, 20, x_bf, l1t, L1b, L2w, lamp);

  // attention core -> abuf8 (fp8)
  attn_kernel<<<16384, 256, 0, stream>>>(qk8, vbuf8, lamp, L2b, abuf8);

  // output: MX-fp8 abuf8 @ wot8 + bias + residual(x_bf), f32
  gemm_womx<<<dim3(512), 512, 0, stream>>>(
      abuf8, wot8, WOb, (float*)d_out, x_bf);
}

// Round 21
// 395.295 us; speedup vs baseline: 4.8316x; 1.0897x over previous
//
#include <hip/hip_runtime.h>
#include <stdint.h>

// ---------------------------------------------------------------------------
// AdaptiveDiffAttention on MI355X (gfx950)
// Round 21 = r17 verbatim (best: 396.4us, absmax 0.0859).
// MX-fp8 everywhere: proj (QK chunked fp8 + V fp8) + fused lambda blocks,
// attn fp8 in/out, WO MX-fp8 with f32+residual epilogue. 256x256 tiles,
// 128KB double-buffered LDS, counted-vmcnt ledger (r13-verified).
// ---------------------------------------------------------------------------

#define ATT_SCALE 0.0625f // 256^-0.5

typedef __attribute__((ext_vector_type(8)))  short   s16x8;
typedef __attribute__((ext_vector_type(4)))  float   f32x4;
typedef __attribute__((ext_vector_type(2)))  float   f32x2;
typedef __attribute__((ext_vector_type(8)))  int     i32x8;
typedef __attribute__((ext_vector_type(8)))  unsigned short u16x8;
typedef __attribute__((ext_vector_type(4)))  unsigned short u16x4;

__device__ __forceinline__ unsigned short f2bf(float f) {
  unsigned u = __float_as_uint(f);
  u += 0x7FFFu + ((u >> 16) & 1u);   // RNE
  return (unsigned short)(u >> 16);
}
__device__ __forceinline__ float bf2f(unsigned short s) {
  return __uint_as_float((unsigned)s << 16);
}

__device__ __forceinline__ unsigned char f2e4m3(float f) {
  unsigned u = __float_as_uint(f);
  unsigned s = (u >> 24) & 0x80u;
  float a = fabsf(f);
  if (a >= 448.f) return (unsigned char)(s | 0x7E);
  if (a < 0.0009765625f) return (unsigned char)s;
  int e = (int)((u >> 23) & 0xFF) - 127;
  if (e < -6) {
    int q = (int)rintf(a * 512.f);
    if (q >= 8) return (unsigned char)(s | 0x08);
    return (unsigned char)(s | q);
  }
  unsigned mant = u & 0x7FFFFFu;
  unsigned mr = mant + 0x7FFFFu + ((mant >> 20) & 1u);
  e += (int)(mr >> 23);
  mant = (mr >> 20) & 7u;
  if (e > 8) return (unsigned char)(s | 0x7E);
  return (unsigned char)(s | ((e + 7) << 3) | mant);
}
__device__ __forceinline__ float e4m3f(unsigned v) {
  unsigned e = (v >> 3) & 15u, m = v & 7u;
  float mag = (e == 0) ? (float)m * 0.001953125f
                       : __uint_as_float(((e + 120u) << 23) | (m << 20));
  return (v & 0x80u) ? -mag : mag;
}

__device__ __forceinline__ unsigned char cvt1_fp8(float v) {
#if __has_builtin(__builtin_amdgcn_cvt_pk_fp8_f32)
  return (unsigned char)(__builtin_amdgcn_cvt_pk_fp8_f32(v, v, 0, false) & 0xff);
#else
  return f2e4m3(v);
#endif
}

__device__ __forceinline__ void dec8(uint2 p, float* o) {
#if __has_builtin(__builtin_amdgcn_cvt_pk_f32_fp8)
  f32x2 a = __builtin_amdgcn_cvt_pk_f32_fp8((int)p.x, false);
  f32x2 b = __builtin_amdgcn_cvt_pk_f32_fp8((int)p.x, true);
  f32x2 c = __builtin_amdgcn_cvt_pk_f32_fp8((int)p.y, false);
  f32x2 d = __builtin_amdgcn_cvt_pk_f32_fp8((int)p.y, true);
  o[0] = a[0]; o[1] = a[1]; o[2] = b[0]; o[3] = b[1];
  o[4] = c[0]; o[5] = c[1]; o[6] = d[0]; o[7] = d[1];
#else
#pragma unroll
  for (int j = 0; j < 4; ++j) o[j]     = e4m3f((p.x >> (8 * j)) & 255u);
#pragma unroll
  for (int j = 0; j < 4; ++j) o[4 + j] = e4m3f((p.y >> (8 * j)) & 255u);
#endif
}

__device__ __forceinline__ void async16(const void* g, void* l) {
  __builtin_amdgcn_global_load_lds((__attribute__((address_space(1))) void*)g,
                                   (__attribute__((address_space(3))) void*)l,
                                   16, 0, 0);
}

// ---------------------------------------------------------------------------
// MX-fp8 proj GEMM + fused lambda.
// Blocks 0..127: lambda. Blocks 128+: [32768,1024]fp8 @ [5120,1024]^T fp8.
//   bn<4096 -> fp8 chunk-blocked qk8 (cols permuted in-chunk, dot-invariant);
//   bn>=4096 -> fp8 row-major vbuf8.
// ---------------------------------------------------------------------------
__global__ __launch_bounds__(512, 2)
void gemm_mx(const unsigned char* __restrict__ A,
             const unsigned char* __restrict__ Bt,
             const float* __restrict__ bias,
             unsigned char* __restrict__ Cout,
             unsigned char* __restrict__ Vout,
             int NN,
             const unsigned short* __restrict__ xbf,
             const unsigned short* __restrict__ lamBt,
             const float* __restrict__ lamL1b,
             const float* __restrict__ lamL2w,
             float* __restrict__ lamp)
{
  __shared__ __align__(16) char lds[131072];
  const int tid  = threadIdx.x;
  const int lane = tid & 63, w = tid >> 6;
  const int wm = w >> 2, wn = w & 3;
  const int li = lane & 15, lc = lane >> 4;

  if (blockIdx.x < 128) {
    // ---- fused lambda block (r12-proven) ----
    const int bm_l = blockIdx.x * 128;
    const int t = tid;
    const size_t aSrc  = (size_t)(bm_l + (t >> 2)) * 2048 + (t & 3) * 8;
    const size_t b0Src = (size_t)(t >> 2) * 2048 + (t & 3) * 8;
    const size_t b1Src = (size_t)(128 + (t >> 2)) * 2048 + (t & 3) * 8;

    f32x4 acc[4][4];
#pragma unroll
    for (int i = 0; i < 4; ++i)
#pragma unroll
      for (int j = 0; j < 4; ++j) acc[i][j] = (f32x4)0.f;

    for (int k0 = 0; k0 < 2048; k0 += 32) {
      async16(xbf   + aSrc  + k0, lds + w * 1024);
      async16(lamBt + b0Src + k0, lds + 8192 + w * 1024);
      async16(lamBt + b1Src + k0, lds + 16384 + w * 1024);
      __syncthreads();
      s16x8 aR[4], bR[4];
#pragma unroll
      for (int m = 0; m < 4; ++m)
        aR[m] = *(const s16x8*)(lds + ((w >> 2) * 64 + m * 16 + li) * 64 + lc * 16);
#pragma unroll
      for (int n = 0; n < 4; ++n)
        bR[n] = *(const s16x8*)(lds + 8192 + ((w & 3) * 64 + n * 16 + li) * 64 + lc * 16);
#pragma unroll
      for (int m = 0; m < 4; ++m)
#pragma unroll
        for (int n = 0; n < 4; ++n)
          acc[m][n] = __builtin_amdgcn_mfma_f32_16x16x32_bf16(aR[m], bR[n], acc[m][n], 0, 0, 0);
      __syncthreads();
    }

    float l2v[4], bvv[4];
#pragma unroll
    for (int n = 0; n < 4; ++n) {
      const int col = (w & 3) * 64 + n * 16 + li;
      l2v[n] = lamL2w[col];
      bvv[n] = lamL1b[col];
    }
#pragma unroll
    for (int m = 0; m < 4; ++m)
#pragma unroll
      for (int j = 0; j < 4; ++j) {
        float part = 0.f;
#pragma unroll
        for (int n = 0; n < 4; ++n)
          part += fmaxf(acc[m][n][j] + bvv[n], 0.f) * l2v[n];
        part += __shfl_xor(part, 1, 64);
        part += __shfl_xor(part, 2, 64);
        part += __shfl_xor(part, 4, 64);
        part += __shfl_xor(part, 8, 64);
        if ((lane & 15) == 0)
          atomicAdd(lamp + bm_l + (w >> 2) * 64 + m * 16 + lc * 4 + j, part);
      }
    return;
  }

  // ---- MX proj path ----
  const int bid = blockIdx.x - 128;
  const int nwg = 2560;
  const int swz = (bid & 7) * (nwg >> 3) + (bid >> 3);
  const int bm = (swz / NN) * 256;
  const int bn = (swz % NN) * 256;

  const int grow   = lane >> 3;
  const int gchunk = ((lane & 7) ^ grow) * 16;
  size_t aSrc[4], bSrc[4];
  int dstKB[4];
#pragma unroll
  for (int i = 0; i < 4; ++i) {
    const int rr = (i * 8 + w) * 8 + grow;
    aSrc[i] = (size_t)(bm + rr) * 1024 + gchunk;
    bSrc[i] = (size_t)(bn + rr) * 1024 + gchunk;
    dstKB[i] = (i * 8 + w) * 1024;
  }

  const int x7   = li & 7;
  const int off0 = ((2 * lc)     ^ x7) * 16;
  const int off1 = ((2 * lc + 1) ^ x7) * 16;
  const int aRow = (wm * 128 + li) * 128;
  const int bRow = 32768 + (wn * 64 + li) * 128;

  f32x4 acc[8][4];
#pragma unroll
  for (int m = 0; m < 8; ++m)
#pragma unroll
    for (int n = 0; n < 4; ++n) acc[m][n] = (f32x4)0.f;

#pragma unroll
  for (int i = 0; i < 4; ++i) {
    async16(A  + aSrc[i], lds + dstKB[i]);
    async16(Bt + bSrc[i], lds + 32768 + dstKB[i]);
  }
#pragma unroll
  for (int i = 0; i < 4; ++i) {
    async16(A  + aSrc[i] + 128, lds + 65536 + dstKB[i]);
    async16(Bt + bSrc[i] + 128, lds + 98304 + dstKB[i]);
  }
  asm volatile("s_waitcnt vmcnt(8)" ::: "memory");
  __builtin_amdgcn_s_barrier();

  for (int t = 0; t < 8; ++t) {
    char* buf = lds + (t & 1) * 65536;

    i32x8 bF[4];
#pragma unroll
    for (int nf = 0; nf < 4; ++nf) {
      const char* p = buf + bRow + nf * 2048;
      uint4* bp = (uint4*)&bF[nf];
      bp[0] = *(const uint4*)(p + off0);
      bp[1] = *(const uint4*)(p + off1);
    }
#pragma unroll
    for (int mh = 0; mh < 2; ++mh) {
      i32x8 aF[4];
#pragma unroll
      for (int mf = 0; mf < 4; ++mf) {
        const char* p = buf + aRow + (mh * 4 + mf) * 2048;
        uint4* ap = (uint4*)&aF[mf];
        ap[0] = *(const uint4*)(p + off0);
        ap[1] = *(const uint4*)(p + off1);
      }
      __builtin_amdgcn_s_setprio(1);
#pragma unroll
      for (int mf = 0; mf < 4; ++mf)
#pragma unroll
        for (int nf = 0; nf < 4; ++nf)
          acc[mh * 4 + mf][nf] = __builtin_amdgcn_mfma_scale_f32_16x16x128_f8f6f4(
              aF[mf], bF[nf], acc[mh * 4 + mf][nf],
              0, 0, 0, 0x7F7F7F7F, 0, 0x7F7F7F7F);
      __builtin_amdgcn_s_setprio(0);
    }
    __builtin_amdgcn_s_barrier();
    if (t + 2 < 8) {
      const size_t kt = (size_t)(t + 2) * 128;
#pragma unroll
      for (int i = 0; i < 4; ++i) {
        async16(A  + aSrc[i] + kt, buf + dstKB[i]);
        async16(Bt + bSrc[i] + kt, buf + 32768 + dstKB[i]);
      }
    }
    if (t < 6) { asm volatile("s_waitcnt vmcnt(8)" ::: "memory"); }
    else       { asm volatile("s_waitcnt vmcnt(0)" ::: "memory"); }
    __builtin_amdgcn_s_barrier();
  }

  float bv[4];
#pragma unroll
  for (int n = 0; n < 4; ++n) bv[n] = bias[bn + wn * 64 + n * 16 + li];

  if (bn < 4096) {
    // fp8 chunk-blocked epilogue -> qk8, packed dword LDS writes.
    // In-chunk col permutation p = li*4+n (dot-invariant: Q,K same map).
    unsigned char* wl0 = (unsigned char*)(lds + w * 12288);
#pragma unroll
    for (int mp = 0; mp < 4; ++mp) {
      unsigned char* wl = wl0 + (mp & 1) * 2560;
#pragma unroll
      for (int mi = 0; mi < 2; ++mi)
#pragma unroll
        for (int jj = 0; jj < 4; ++jj) {
          unsigned d = 0;
#pragma unroll
          for (int n = 0; n < 4; ++n) {
            float v = acc[mp * 2 + mi][n][jj] + bv[n];
            d |= (unsigned)cvt1_fp8(v) << (8 * n);
          }
          *(unsigned*)(wl + (mi * 16 + lc * 4 + jj) * 80 + li * 4) = d;
        }
      const size_t base = (size_t)((bm + wm * 128 + mp * 32) >> 5) * 131072
                        + (size_t)((bn >> 6) + wn) * 2048;
      uint4 v0 = *(const uint4*)(wl + (lane >> 2) * 80 + (lane & 3) * 16);
      *(uint4*)(Cout + base + lane * 16) = v0;
      uint4 v1 = *(const uint4*)(wl + (16 + (lane >> 2)) * 80 + (lane & 3) * 16);
      *(uint4*)(Cout + base + 1024 + lane * 16) = v1;
    }
  } else {
    // fp8 epilogue -> vbuf8 [.,1024] row-major (no permutation)
    unsigned char* wl0 = (unsigned char*)(lds + w * 12288);
    const int cb = bn - 4096;
#pragma unroll
    for (int mp = 0; mp < 4; ++mp) {
      unsigned char* wl = wl0 + (mp & 1) * 2560;
#pragma unroll
      for (int mi = 0; mi < 2; ++mi)
#pragma unroll
        for (int n = 0; n < 4; ++n)
#pragma unroll
          for (int jj = 0; jj < 4; ++jj) {
            float v = acc[mp * 2 + mi][n][jj] + bv[n];
            wl[(mi * 16 + lc * 4 + jj) * 72 + n * 16 + li] = cvt1_fp8(v);
          }
#pragma unroll
      for (int i = 0; i < 4; ++i) {
        const int rr = i * 8 + (lane >> 3);
        uint2 vv = *(const uint2*)(wl + rr * 72 + (lane & 7) * 8);
        const size_t gi = (size_t)(bm + wm * 128 + mp * 32 + rr) * 1024
                        + cb + wn * 64 + (lane & 7) * 8;
        *(uint2*)(Vout + gi) = vv;
      }
    }
  }
}

// ---------------------------------------------------------------------------
// MX-fp8 WO GEMM: out[32768,1024](f32) = abuf8 @ wot8^T + WOb + res(bf16).
// ---------------------------------------------------------------------------
__global__ __launch_bounds__(512, 2)
void gemm_womx(const unsigned char* __restrict__ A,
               const unsigned char* __restrict__ Bt,
               const float* __restrict__ bias,
               float* __restrict__ Cout,
               const unsigned short* __restrict__ res)
{
  __shared__ __align__(16) char lds[131072];
  const int tid  = threadIdx.x;
  const int lane = tid & 63, w = tid >> 6;
  const int wm = w >> 2, wn = w & 3;
  const int li = lane & 15, lc = lane >> 4;

  const int swz = (blockIdx.x & 7) * 64 + (blockIdx.x >> 3);
  const int bm = (swz >> 2) * 256;
  const int bn = (swz & 3) * 256;

  const int grow   = lane >> 3;
  const int gchunk = ((lane & 7) ^ grow) * 16;
  size_t aSrc[4], bSrc[4];
  int dstKB[4];
#pragma unroll
  for (int i = 0; i < 4; ++i) {
    const int rr = (i * 8 + w) * 8 + grow;
    aSrc[i] = (size_t)(bm + rr) * 1024 + gchunk;
    bSrc[i] = (size_t)(bn + rr) * 1024 + gchunk;
    dstKB[i] = (i * 8 + w) * 1024;
  }

  const int x7   = li & 7;
  const int off0 = ((2 * lc)     ^ x7) * 16;
  const int off1 = ((2 * lc + 1) ^ x7) * 16;
  const int aRow = (wm * 128 + li) * 128;
  const int bRow = 32768 + (wn * 64 + li) * 128;

  f32x4 acc[8][4];
#pragma unroll
  for (int m = 0; m < 8; ++m)
#pragma unroll
    for (int n = 0; n < 4; ++n) acc[m][n] = (f32x4)0.f;

#pragma unroll
  for (int i = 0; i < 4; ++i) {
    async16(A  + aSrc[i], lds + dstKB[i]);
    async16(Bt + bSrc[i], lds + 32768 + dstKB[i]);
  }
#pragma unroll
  for (int i = 0; i < 4; ++i) {
    async16(A  + aSrc[i] + 128, lds + 65536 + dstKB[i]);
    async16(Bt + bSrc[i] + 128, lds + 98304 + dstKB[i]);
  }
  asm volatile("s_waitcnt vmcnt(8)" ::: "memory");
  __builtin_amdgcn_s_barrier();

  for (int t = 0; t < 8; ++t) {
    char* buf = lds + (t & 1) * 65536;

    i32x8 bF[4];
#pragma unroll
    for (int nf = 0; nf < 4; ++nf) {
      const char* p = buf + bRow + nf * 2048;
      uint4* bp = (uint4*)&bF[nf];
      bp[0] = *(const uint4*)(p + off0);
      bp[1] = *(const uint4*)(p + off1);
    }
#pragma unroll
    for (int mh = 0; mh < 2; ++mh) {
      i32x8 aF[4];
#pragma unroll
      for (int mf = 0; mf < 4; ++mf) {
        const char* p = buf + aRow + (mh * 4 + mf) * 2048;
        uint4* ap = (uint4*)&aF[mf];
        ap[0] = *(const uint4*)(p + off0);
        ap[1] = *(const uint4*)(p + off1);
      }
      __builtin_amdgcn_s_setprio(1);
#pragma unroll
      for (int mf = 0; mf < 4; ++mf)
#pragma unroll
        for (int nf = 0; nf < 4; ++nf)
          acc[mh * 4 + mf][nf] = __builtin_amdgcn_mfma_scale_f32_16x16x128_f8f6f4(
              aF[mf], bF[nf], acc[mh * 4 + mf][nf],
              0, 0, 0, 0x7F7F7F7F, 0, 0x7F7F7F7F);
      __builtin_amdgcn_s_setprio(0);
    }
    __builtin_amdgcn_s_barrier();
    if (t + 2 < 8) {
      const size_t kt = (size_t)(t + 2) * 128;
#pragma unroll
      for (int i = 0; i < 4; ++i) {
        async16(A  + aSrc[i] + kt, buf + dstKB[i]);
        async16(Bt + bSrc[i] + kt, buf + 32768 + dstKB[i]);
      }
    }
    if (t < 6) { asm volatile("s_waitcnt vmcnt(8)" ::: "memory"); }
    else       { asm volatile("s_waitcnt vmcnt(0)" ::: "memory"); }
    __builtin_amdgcn_s_barrier();
  }

  float bv[4];
#pragma unroll
  for (int n = 0; n < 4; ++n) bv[n] = bias[bn + wn * 64 + n * 16 + li];

  float* wl0 = (float*)(lds + w * 12288);
#pragma unroll
  for (int m = 0; m < 8; ++m) {
    float* wl = wl0 + (m & 1) * 1088;
#pragma unroll
    for (int n = 0; n < 4; ++n)
#pragma unroll
      for (int jj = 0; jj < 4; ++jj)
        wl[(lc * 4 + jj) * 68 + li + n * 16] = acc[m][n][jj] + bv[n];
#pragma unroll
    for (int i = 0; i < 4; ++i) {
      const int rr = i * 4 + lc;
      f32x4 vv = *(const f32x4*)(wl + rr * 68 + li * 4);
      const size_t gi = (size_t)(bm + wm * 128 + m * 16 + rr) * 1024
                      + bn + wn * 64 + li * 4;
      const u16x4 rv = *(const u16x4*)(res + gi);
      f32x4 ov;
#pragma unroll
      for (int jj = 0; jj < 4; ++jj) ov[jj] = vv[jj] + bf2f(rv[jj]);
      *(f32x4*)(Cout + gi) = ov;
    }
  }
}

// ---------------------------------------------------------------------------
// Attention core. qk8 chunk-blocked fp8, vbuf8 fp8; writes abuf8 fp8.
// ---------------------------------------------------------------------------
__global__ __launch_bounds__(256)
void attn_kernel(const unsigned char* __restrict__ qk8,
                 const unsigned char* __restrict__ vbuf8,
                 const float* __restrict__ lam_pre,
                 const float* __restrict__ L2b,
                 unsigned char* __restrict__ aout8)
{
  const int b = blockIdx.x;
  const int hd = threadIdx.x >> 6;
  const int lane = threadIdx.x & 63;
  const int g = lane >> 5;
  const int l5 = lane & 31;
  const size_t row = (size_t)(2 * b + g);

  const size_t cbase = (row >> 5) * 131072
                     + (size_t)(hd * 4 + (l5 >> 3)) * 2048
                     + (row & 31) * 64 + (l5 & 7) * 8;
  const uint2 p1 = *(const uint2*)(qk8 + cbase);
  const uint2 p2 = *(const uint2*)(qk8 + cbase + 32768);
  const uint2 p3 = *(const uint2*)(qk8 + cbase + 65536);
  const uint2 p4 = *(const uint2*)(qk8 + cbase + 98304);
  const uint2 pv = *(const uint2*)(vbuf8 + row * 1024 + hd * 256 + l5 * 8);

  float q1[8], k1[8], q2[8], k2[8], vf[8];
  dec8(p1, q1); dec8(p2, k1); dec8(p3, q2); dec8(p4, k2);
  dec8(pv, vf);

  float ss1 = 0.f, sc1 = 0.f, ss2 = 0.f, sc2 = 0.f;
#pragma unroll
  for (int j = 0; j < 8; ++j) {
    const float k1o = __shfl_xor(k1[j], 32, 64);
    const float k2o = __shfl_xor(k2[j], 32, 64);
    ss1 += q1[j] * k1[j]; sc1 += q1[j] * k1o;
    ss2 += q2[j] * k2[j]; sc2 += q2[j] * k2o;
  }
#pragma unroll
  for (int m = 16; m >= 1; m >>= 1) {
    ss1 += __shfl_xor(ss1, m, 64); sc1 += __shfl_xor(sc1, m, 64);
    ss2 += __shfl_xor(ss2, m, 64); sc2 += __shfl_xor(sc2, m, 64);
  }

  float e0 = ss1 * ATT_SCALE, e1 = sc1 * ATT_SCALE;
  float mx = fmaxf(e0, e1);
  float xs = expf(e0 - mx), xc = expf(e1 - mx);
  float inv = 1.f / (xs + xc);
  const float a1s = xs * inv, a1c = xc * inv;

  e0 = ss2 * ATT_SCALE; e1 = sc2 * ATT_SCALE;
  mx = fmaxf(e0, e1);
  xs = expf(e0 - mx); xc = expf(e1 - mx);
  inv = 1.f / (xs + xc);
  const float a2s = xs * inv, a2c = xc * inv;

  const float lm = 1.f / (1.f + expf(-(lam_pre[b] + L2b[0])));
  const float ps = fmaxf(a1s - lm * a2s, 0.f);
  const float pc = fmaxf(a1c - lm * a2c, 0.f);

  unsigned lo = 0, hi = 0;
#pragma unroll
  for (int j = 0; j < 4; ++j) {
    const float vo = __shfl_xor(vf[j], 32, 64);
    lo |= (unsigned)cvt1_fp8(ps * vf[j] + pc * vo) << (8 * j);
  }
#pragma unroll
  for (int j = 4; j < 8; ++j) {
    const float vo = __shfl_xor(vf[j], 32, 64);
    hi |= (unsigned)cvt1_fp8(ps * vf[j] + pc * vo) << (8 * (j - 4));
  }
  uint2 o2; o2.x = lo; o2.y = hi;
  *(uint2*)(aout8 + row * 1024 + hd * 256 + l5 * 8) = o2;
}

// ---------------------------------------------------------------------------
// Fused prep: z 0-4 -> qw8 fp8 (Q1,K1,Q2,K2,V), z 5 -> wot8 fp8,
// z 6-21 x -> x_bf + x_f8, z 22 L1 transpose, z 23 bias concat + lamp zero.
// ---------------------------------------------------------------------------
__global__ void prep_k(const float* __restrict__ s0, const float* __restrict__ s1,
                       const float* __restrict__ s2, const float* __restrict__ s3,
                       const float* __restrict__ s4, const float* __restrict__ s5,
                       const float* __restrict__ L1w,
                       const float* __restrict__ b0, const float* __restrict__ b1,
                       const float* __restrict__ b2, const float* __restrict__ b3,
                       const float* __restrict__ b4,
                       const float* __restrict__ x,
                       unsigned char* __restrict__ qw8,
                       unsigned char* __restrict__ wot8,
                       unsigned short* __restrict__ l1t,
                       float* __restrict__ bcat,
                       unsigned short* __restrict__ x_bf,
                       unsigned char* __restrict__ x_f8,
                       float* __restrict__ lamp)
{
  __shared__ float tile[32][33];
  const int z = blockIdx.z;
  const int tx = threadIdx.x, ty = threadIdx.y;

  if (z < 6) {
    const float* W;
    switch (z) {
      case 0: W = s0; break;
      case 1: W = s1; break;
      case 2: W = s2; break;
      case 3: W = s3; break;
      case 4: W = s4; break;
      default: W = s5; break;
    }
    const int bn = blockIdx.x * 32, bk = blockIdx.y * 32;
#pragma unroll
    for (int i = ty; i < 32; i += 8)
      tile[i][tx] = W[(size_t)(bk + i) * 1024 + bn + tx];
    __syncthreads();
    unsigned char* Wt = (z < 5) ? (qw8 + (size_t)z * 1048576) : wot8;
#pragma unroll
    for (int i = ty; i < 32; i += 8)
      Wt[(size_t)(bn + i) * 1024 + bk + tx] = cvt1_fp8(tile[tx][i]);
    return;
  }
  if (z < 22) {
    const int c = (z - 6) * 1024 + blockIdx.y * 32 + blockIdx.x;
    const int i = c * 256 + ty * 32 + tx;
    const float4* p = (const float4*)x + (size_t)i * 2;
    float4 a = p[0], b = p[1];
    float f[8] = {a.x, a.y, a.z, a.w, b.x, b.y, b.z, b.w};
    u16x8 v; unsigned lo = 0, hi = 0;
#pragma unroll
    for (int j = 0; j < 8; ++j) v[j] = f2bf(f[j]);
#pragma unroll
    for (int j = 0; j < 4; ++j) lo |= (unsigned)cvt1_fp8(f[j]) << (8 * j);
#pragma unroll
    for (int j = 0; j < 4; ++j) hi |= (unsigned)cvt1_fp8(f[4 + j]) << (8 * j);
    *(u16x8*)(x_bf + (size_t)i * 8) = v;
    uint2 c8; c8.x = lo; c8.y = hi;
    *(uint2*)(x_f8 + (size_t)i * 8) = c8;
    return;
  }
  if (z == 22) {
    const int idx = blockIdx.y * 32 + blockIdx.x;
    if (idx >= 512) return;
    const int bn = (idx & 7) * 32, bk = (idx >> 3) * 32;
#pragma unroll
    for (int i = ty; i < 32; i += 8)
      tile[i][tx] = L1w[(size_t)(bk + i) * 256 + bn + tx];
    __syncthreads();
#pragma unroll
    for (int i = ty; i < 32; i += 8)
      l1t[(size_t)(bn + i) * 2048 + bk + tx] = f2bf(tile[tx][i]);
    return;
  }
  const int idx = blockIdx.y * 32 + blockIdx.x;
  const int t = ty * 32 + tx;
  if (idx < 20) {
    const int i = idx * 256 + t;
    const float* src;
    switch (i >> 10) {
      case 0: src = b0; break;
      case 1: src = b1; break;
      case 2: src = b2; break;
      case 3: src = b3; break;
      default: src = b4; break;
    }
    bcat[i] = src[i & 1023];
  } else if (idx < 84) {
    lamp[(idx - 20) * 256 + t] = 0.f;
  }
}

// ---------------------------------------------------------------------------
extern "C" void kernel_launch(void* const* d_in, const int* in_sizes, int n_in,
                              void* d_out, int out_size, void* d_ws, size_t ws_size,
                              hipStream_t stream)
{
  const float* x    = (const float*)d_in[0];
  const float* WQ1w = (const float*)d_in[1];  const float* WQ1b = (const float*)d_in[2];
  const float* WK1w = (const float*)d_in[3];  const float* WK1b = (const float*)d_in[4];
  const float* WQ2w = (const float*)d_in[5];  const float* WQ2b = (const float*)d_in[6];
  const float* WK2w = (const float*)d_in[7];  const float* WK2b = (const float*)d_in[8];
  const float* WVw  = (const float*)d_in[9];  const float* WVb  = (const float*)d_in[10];
  const float* WOw  = (const float*)d_in[11]; const float* WOb  = (const float*)d_in[12];
  const float* L1w  = (const float*)d_in[13]; const float* L1b  = (const float*)d_in[14];
  const float* L2w  = (const float*)d_in[15]; const float* L2b  = (const float*)d_in[16];

  char* ws = (char*)d_ws;
  size_t off = 0;
  unsigned short* x_bf  = (unsigned short*)(ws + off); off += (size_t)33554432 * 2;  // 64MB
  unsigned char*  x_f8  = (unsigned char*)(ws + off);  off += (size_t)33554432;      // 32MB
  unsigned char*  qw8   = (unsigned char*)(ws + off);  off += (size_t)5242880;       // 5MB
  unsigned char*  wot8  = (unsigned char*)(ws + off);  off += (size_t)1048576;       // 1MB
  unsigned short* l1t   = (unsigned short*)(ws + off); off += (size_t)524288 * 2;    // 1MB
  float*          bcat  = (float*)(ws + off);          off += (size_t)5120 * 4;
  unsigned char*  qk8   = (unsigned char*)(ws + off);  off += (size_t)32768 * 4096;  // 128MB
  unsigned char*  vbuf8 = (unsigned char*)(ws + off);  off += (size_t)33554432;      // 32MB
  unsigned char*  abuf8 = (unsigned char*)(ws + off);  off += (size_t)33554432;      // 32MB
  float*          lamp  = (float*)(ws + off);          off += (size_t)16384 * 4;

  // fused prep
  prep_k<<<dim3(32, 32, 24), dim3(32, 8), 0, stream>>>(
      WQ1w, WK1w, WQ2w, WK2w, WVw, WOw, L1w,
      WQ1b, WK1b, WQ2b, WK2b, WVb, x,
      qw8, wot8, l1t, bcat, x_bf, x_f8, lamp);

  // MX projections (QK fp8 + V fp8 out) + fused lambda (blocks 0-127)
  gemm_mx<<<dim3(128 + 2560), 512, 0, stream>>>(
      x_f8, qw8, bcat, qk8, vbuf8, 20, x_bf, l1t, L1b, L2w, lamp);

  // attention core -> abuf8 (fp8)
  attn_kernel<<<16384, 256, 0, stream>>>(qk8, vbuf8, lamp, L2b, abuf8);

  // output: MX-fp8 abuf8 @ wot8 + bias + residual(x_bf), f32
  gemm_womx<<<dim3(512), 512, 0, stream>>>(
      abuf8, wot8, WOb, (float*)d_out, x_bf);
}